// Round 8
// baseline (507.880 us; speedup 1.0000x reference)
//
#include <hip/hip_runtime.h>

// Problem: STATE_LEN=2048, SEQ_LEN=4096, HIDDEN=2048, all fp32 inputs.
// out = softmax(out_state @ W @ history^T, axis=-1)   (bias drops out of softmax)
//
// Precision: split each fp32 operand into bf16 hi + bf16 lo; MFMA computes
// hi*hi + hi*lo + lo*hi (drop lo*lo) -> ~4e-3 output error.
//
// R8: LDS-free GEMM. R2/R6/R7 showed duration invariant to occupancy at
// MfmaUtil=41% -> shared-resource bound; arithmetic points at the LDS pipe
// (96 KB/block-iter ~ 48 B/cyc vs ~85 ceiling) + barrier structure.
// Operands are K-contiguous, so MFMA fragments load DIRECTLY from global
// (global_load_dwordx4, L1/L2-served). No __shared__, no __syncthreads in
// the K-loop at all -> waves pipeline freely; LDS traffic = 0.

#define STATE_LEN 2048
#define SEQ_LEN   4096
#define HIDDEN    2048

typedef __bf16 bf16x8 __attribute__((ext_vector_type(8)));
typedef float f32x4 __attribute__((ext_vector_type(4)));

__device__ __forceinline__ unsigned short f32_to_bf16(float f) {
  unsigned u = __float_as_uint(f);
  u += 0x7FFFu + ((u >> 16) & 1u);   // round-to-nearest-even
  return (unsigned short)(u >> 16);
}
__device__ __forceinline__ float bf16_to_f32(unsigned short h) {
  return __uint_as_float(((unsigned)h) << 16);
}

// ---------------- fp32 -> (bf16 hi, bf16 lo) elementwise split ----------------
__global__ __launch_bounds__(256) void split_kernel(
    const float* __restrict__ in, unsigned short* __restrict__ hi,
    unsigned short* __restrict__ lo, int n) {
  int i = (blockIdx.x * 256 + threadIdx.x) * 4;
  if (i >= n) return;
  float4 v = *(const float4*)&in[i];
  ushort4 h, l;
  h.x = f32_to_bf16(v.x); l.x = f32_to_bf16(v.x - bf16_to_f32(h.x));
  h.y = f32_to_bf16(v.y); l.y = f32_to_bf16(v.y - bf16_to_f32(h.y));
  h.z = f32_to_bf16(v.z); l.z = f32_to_bf16(v.z - bf16_to_f32(h.z));
  h.w = f32_to_bf16(v.w); l.w = f32_to_bf16(v.w - bf16_to_f32(h.w));
  *(ushort4*)&hi[i] = h;
  *(ushort4*)&lo[i] = l;
}

// ------------- fp32 -> transposed (bf16 hi, bf16 lo): Wt[k][h] = W[h][k] -------------
__global__ __launch_bounds__(256) void transpose_split_kernel(
    const float* __restrict__ in, unsigned short* __restrict__ hi,
    unsigned short* __restrict__ lo, int rows, int cols) {
  __shared__ float tile[32][33];
  const int bx = blockIdx.x * 32;  // col base
  const int by = blockIdx.y * 32;  // row base
  const int tx = threadIdx.x;      // 0..31
  const int ty = threadIdx.y;      // 0..7
#pragma unroll
  for (int i = 0; i < 32; i += 8)
    tile[ty + i][tx] = in[(size_t)(by + ty + i) * cols + (bx + tx)];
  __syncthreads();
#pragma unroll
  for (int i = 0; i < 32; i += 8) {
    float x = tile[tx][ty + i];
    unsigned short h = f32_to_bf16(x);
    unsigned short l = f32_to_bf16(x - bf16_to_f32(h));
    size_t o = (size_t)(bx + ty + i) * rows + (by + tx);
    hi[o] = h;
    lo[o] = l;
  }
}

// ---- p0+p1+p2+p3 -> split bf16 (hi/lo) ----
__global__ __launch_bounds__(256) void reduce_split4(
    const float* __restrict__ p0, const float* __restrict__ p1,
    const float* __restrict__ p2, const float* __restrict__ p3,
    unsigned short* __restrict__ hi, unsigned short* __restrict__ lo, int n) {
  int i = (blockIdx.x * 256 + threadIdx.x) * 4;
  if (i >= n) return;
  float4 a = *(const float4*)&p0[i];
  float4 b = *(const float4*)&p1[i];
  float4 c = *(const float4*)&p2[i];
  float4 d = *(const float4*)&p3[i];
  a.x = (a.x + b.x) + (c.x + d.x);
  a.y = (a.y + b.y) + (c.y + d.y);
  a.z = (a.z + b.z) + (c.z + d.z);
  a.w = (a.w + b.w) + (c.w + d.w);
  ushort4 h, l;
  h.x = f32_to_bf16(a.x); l.x = f32_to_bf16(a.x - bf16_to_f32(h.x));
  h.y = f32_to_bf16(a.y); l.y = f32_to_bf16(a.y - bf16_to_f32(h.y));
  h.z = f32_to_bf16(a.z); l.z = f32_to_bf16(a.z - bf16_to_f32(h.z));
  h.w = f32_to_bf16(a.w); l.w = f32_to_bf16(a.w - bf16_to_f32(h.w));
  *(ushort4*)&hi[i] = h;
  *(ushort4*)&lo[i] = l;
}

// ------------- LDS-free split-bf16 GEMM, C[m][n] = sum_k A[m][k]*B[n][k] -------------
// A: [M,K] row-major (hi/lo bf16), B: [N,K] row-major (hi/lo bf16).
// Block tile 128x128, 2x2 waves, per-wave 64x64, 16x16x32 MFMA.
// Fragments load straight from global (K-contiguous rows): lane reads
// row = base + sub*16 + (lane&15), k = k0 + (lane>>4)*8  -> b128 per frag.
// No LDS, no barriers. KSPLIT>1: blockIdx.z picks K-chunk, partial -> Cf{z}.
template <int KSPLIT>
__global__ __launch_bounds__(256, 2) void gemm_direct(
    const unsigned short* __restrict__ Ahi, const unsigned short* __restrict__ Alo,
    const unsigned short* __restrict__ Bhi, const unsigned short* __restrict__ Blo,
    float* __restrict__ Cf0, float* __restrict__ Cf1,
    float* __restrict__ Cf2, float* __restrict__ Cf3, int M, int N, int K) {
  const int t = threadIdx.x;
  const int tileM = blockIdx.y * 128;
  const int tileN = blockIdx.x * 128;
  const int z = (KSPLIT > 1) ? blockIdx.z : 0;
  const int kBase = z * (K / KSPLIT);
  const int iters = (K / KSPLIT) / 32;
  float* Cf = Cf0;
  if (KSPLIT > 1) {
    if (z == 1) Cf = Cf1;
    else if (z == 2) Cf = Cf2;
    else if (z == 3) Cf = Cf3;
  }

  const int lane = t & 63;
  const int wave = t >> 6;
  const int wm = wave >> 1;  // 2x2 wave grid
  const int wn = wave & 1;
  const int lr = lane & 15;
  const int kqc = lane >> 4;  // k-chunk (8 bf16 = 16 B)

  // per-lane fragment base pointers (advance by 32 elements per iter)
  const size_t aRow = (size_t)(tileM + wm * 64 + lr) * K + kBase + kqc * 8;
  const size_t bRow = (size_t)(tileN + wn * 64 + lr) * K + kBase + kqc * 8;
  const unsigned short* pAh = Ahi + aRow;
  const unsigned short* pAl = Alo + aRow;
  const unsigned short* pBh = Bhi + bRow;
  const unsigned short* pBl = Blo + bRow;
  const size_t rstep = (size_t)16 * K;  // 16 rows between m-subtiles

  f32x4 acc[4][4] = {};

  for (int it = 0; it < iters; ++it) {
    bf16x8 ah[4], al[4], bh[4], bl[4];
#pragma unroll
    for (int mi = 0; mi < 4; ++mi) {
      ah[mi] = *(const bf16x8*)(pAh + mi * rstep);
      al[mi] = *(const bf16x8*)(pAl + mi * rstep);
    }
#pragma unroll
    for (int ni = 0; ni < 4; ++ni) {
      bh[ni] = *(const bf16x8*)(pBh + ni * rstep);
      bl[ni] = *(const bf16x8*)(pBl + ni * rstep);
    }
#pragma unroll
    for (int mi = 0; mi < 4; ++mi)
#pragma unroll
      for (int ni = 0; ni < 4; ++ni) {
        acc[mi][ni] = __builtin_amdgcn_mfma_f32_16x16x32_bf16(ah[mi], bh[ni], acc[mi][ni], 0, 0, 0);
        acc[mi][ni] = __builtin_amdgcn_mfma_f32_16x16x32_bf16(ah[mi], bl[ni], acc[mi][ni], 0, 0, 0);
        acc[mi][ni] = __builtin_amdgcn_mfma_f32_16x16x32_bf16(al[mi], bh[ni], acc[mi][ni], 0, 0, 0);
      }
    pAh += 32; pAl += 32; pBh += 32; pBl += 32;
  }

  // epilogue: C/D layout col=lane&15, row=(lane>>4)*4+reg
#pragma unroll
  for (int mi = 0; mi < 4; ++mi)
#pragma unroll
    for (int ni = 0; ni < 4; ++ni)
#pragma unroll
      for (int e = 0; e < 4; ++e) {
        const int row = tileM + wm * 64 + mi * 16 + (lane >> 4) * 4 + e;
        const int col = tileN + wn * 64 + ni * 16 + lr;
        Cf[(size_t)row * N + col] = acc[mi][ni][e];
      }
}

// -------- fused: out[row] = softmax(out[row] + part[row]) over 4096 cols --------
__global__ __launch_bounds__(256) void reduce_softmax(float* __restrict__ d,
                                                      const float* __restrict__ part,
                                                      int cols) {
  const int row = blockIdx.x;
  float* p = d + (size_t)row * cols;
  const float* q = part + (size_t)row * cols;
  const int t = threadIdx.x;
  const int lane = t & 63;
  const int wave = t >> 6;
  __shared__ float sred[4];

  float4 v[4];
  float m = -3.0e38f;
#pragma unroll
  for (int k = 0; k < 4; ++k) {
    float4 a = *(const float4*)&p[(t + k * 256) * 4];
    float4 b = *(const float4*)&q[(t + k * 256) * 4];
    a.x += b.x; a.y += b.y; a.z += b.z; a.w += b.w;
    v[k] = a;
    m = fmaxf(m, fmaxf(fmaxf(a.x, a.y), fmaxf(a.z, a.w)));
  }
#pragma unroll
  for (int off = 32; off > 0; off >>= 1) m = fmaxf(m, __shfl_xor(m, off, 64));
  if (lane == 0) sred[wave] = m;
  __syncthreads();
  m = fmaxf(fmaxf(sred[0], sred[1]), fmaxf(sred[2], sred[3]));
  __syncthreads();

  float s = 0.f;
#pragma unroll
  for (int k = 0; k < 4; ++k) {
    v[k].x = __expf(v[k].x - m);
    v[k].y = __expf(v[k].y - m);
    v[k].z = __expf(v[k].z - m);
    v[k].w = __expf(v[k].w - m);
    s += (v[k].x + v[k].y) + (v[k].z + v[k].w);
  }
#pragma unroll
  for (int off = 32; off > 0; off >>= 1) s += __shfl_xor(s, off, 64);
  if (lane == 0) sred[wave] = s;
  __syncthreads();
  s = (sred[0] + sred[1]) + (sred[2] + sred[3]);
  const float inv = 1.0f / s;
#pragma unroll
  for (int k = 0; k < 4; ++k) {
    v[k].x *= inv; v[k].y *= inv; v[k].z *= inv; v[k].w *= inv;
    *(float4*)&p[(t + k * 256) * 4] = v[k];
  }
}

extern "C" void kernel_launch(void* const* d_in, const int* in_sizes, int n_in,
                              void* d_out, int out_size, void* d_ws, size_t ws_size,
                              hipStream_t stream) {
  const float* out_state = (const float*)d_in[0];  // [2048, 2048]
  const float* history   = (const float*)d_in[1];  // [4096, 2048]
  const float* W         = (const float*)d_in[2];  // [2048, 2048]
  // d_in[3] = b : softmax-invariant, unused.
  float* out = (float*)d_out;                      // [2048, 4096] fp32

  char* ws = (char*)d_ws;
  const size_t MB = 1ull << 20;
  unsigned short* ohi  = (unsigned short*)(ws + 0 * MB);   // 8 MB  out_state hi
  unsigned short* olo  = (unsigned short*)(ws + 8 * MB);   // 8 MB  out_state lo
  unsigned short* wthi = (unsigned short*)(ws + 16 * MB);  // 8 MB  W^T hi
  unsigned short* wtlo = (unsigned short*)(ws + 24 * MB);  // 8 MB  W^T lo
  unsigned short* hhi  = (unsigned short*)(ws + 32 * MB);  // 16 MB history hi
  unsigned short* hlo  = (unsigned short*)(ws + 48 * MB);  // 16 MB history lo
  float*          pws  = (float*)(ws + 64 * MB);           // 32 MB scratch partials
  // GEMM1 partials: z0,z1 in pws; z2,z3 in d_out (scratch, 32 MB exact)
  float* g1p0 = pws;
  float* g1p1 = pws + (size_t)STATE_LEN * HIDDEN;
  float* g1p2 = out;
  float* g1p3 = out + (size_t)STATE_LEN * HIDDEN;
  // T split-bf16 reuses ws[0:16] (ohi/olo dead after GEMM1)
  unsigned short* thi = (unsigned short*)(ws + 0 * MB);
  unsigned short* tlo = (unsigned short*)(ws + 8 * MB);

  // 1) split out_state
  split_kernel<<<(STATE_LEN * HIDDEN) / 1024, 256, 0, stream>>>(out_state, ohi, olo,
                                                                STATE_LEN * HIDDEN);
  // 2) transpose+split W -> Wt[k][h]
  transpose_split_kernel<<<dim3(HIDDEN / 32, HIDDEN / 32), dim3(32, 8), 0, stream>>>(
      W, wthi, wtlo, HIDDEN, HIDDEN);
  // 3) split history
  split_kernel<<<(SEQ_LEN * HIDDEN) / 1024, 256, 0, stream>>>(history, hhi, hlo,
                                                              SEQ_LEN * HIDDEN);
  // 4) T partials: KSPLIT=4 -> 16x16x4 = 1024 blocks, LDS-free
  gemm_direct<4>
      <<<dim3(HIDDEN / 128, STATE_LEN / 128, 4), 256, 0, stream>>>(
          ohi, olo, wthi, wtlo, g1p0, g1p1, g1p2, g1p3, STATE_LEN, HIDDEN, HIDDEN);
  // 4b) T = sum of 4 partials, split to bf16 hi/lo (into dead ohi/olo space)
  reduce_split4<<<(STATE_LEN * HIDDEN) / 1024, 256, 0, stream>>>(
      g1p0, g1p1, g1p2, g1p3, thi, tlo, STATE_LEN * HIDDEN);
  // 5) scores partials: KSPLIT=2 -> 32x16x2 = 1024 blocks; z0 -> d_out, z1 -> pws
  gemm_direct<2>
      <<<dim3(SEQ_LEN / 128, STATE_LEN / 128, 2), 256, 0, stream>>>(
          thi, tlo, hhi, hlo, out, pws, nullptr, nullptr, STATE_LEN, SEQ_LEN, HIDDEN);
  // 6) fused partial-add + row softmax
  reduce_softmax<<<STATE_LEN, 256, 0, stream>>>(out, pws, SEQ_LEN);
}

// Round 9
// 362.668 us; speedup vs baseline: 1.4004x; 1.4004x over previous
//
#include <hip/hip_runtime.h>

// out = softmax(out_state @ W @ history^T, axis=-1); bias drops out of softmax.
// STATE_LEN=2048, SEQ_LEN=4096, HIDDEN=2048, fp32 in/out.
// Precision: split-bf16 (hi+lo), 3-term MFMA (hh+hl+lh) -> ~4e-3 absmax.
//
// R9: LDS-free, barrier-free GEMM over FRAGMENT-ORDER operands.
//  R8 failed on coalescing (lanes 4KB apart). Fix: pre-pack every operand as
//  16-row x 32-k panels, 64 lanes' 16B chunks contiguous:
//    addr(r,k) = ((  (r>>4)*Kc + (k>>5) )*64 + (r&15) + 16*((k>>3)&3) )*8 + (k&7)
//  -> each MFMA fragment load = ONE coalesced 1KB global_load_dwordx4.
//  GEMM has no __shared__, no __syncthreads: waves pipeline loads across
//  iterations (vmcnt>0), LDS pipe (R2-R7's wall) is idle.

#define STATE_LEN 2048
#define SEQ_LEN   4096
#define HIDDEN    2048

typedef __bf16 bf16x8 __attribute__((ext_vector_type(8)));
typedef float f32x4 __attribute__((ext_vector_type(4)));
typedef unsigned short u16x8 __attribute__((ext_vector_type(8)));

__device__ __forceinline__ unsigned short f32_to_bf16(float f) {
  unsigned u = __float_as_uint(f);
  u += 0x7FFFu + ((u >> 16) & 1u);   // round-to-nearest-even
  return (unsigned short)(u >> 16);
}
__device__ __forceinline__ float bf16_to_f32(unsigned short h) {
  return __uint_as_float(((unsigned)h) << 16);
}

// ---------- pack 'in' (fp32) into fragment-order split bf16 hi/lo ----------
// Operand X[R][K]; X[r][k] = TRANS ? in[k][r] : in[r][k]. One block = 64x64 tile.
template <bool TRANS>
__global__ __launch_bounds__(256) void pack_frag(
    const float* __restrict__ in, int inCols,
    unsigned short* __restrict__ hi, unsigned short* __restrict__ lo, int K) {
  __shared__ float tile[64][65];
  const int t = threadIdx.x;
  const int r0 = blockIdx.y * 64;  // operand row base
  const int k0 = blockIdx.x * 64;  // operand k base
  const int lr = t >> 4;
  const int c4 = (t & 15) * 4;
#pragma unroll
  for (int pass = 0; pass < 4; ++pass) {
    const int row = pass * 16 + lr;
    const float* src = TRANS ? &in[(size_t)(k0 + row) * inCols + r0 + c4]
                             : &in[(size_t)(r0 + row) * inCols + k0 + c4];
    float4 v = *(const float4*)src;
    // tile[i][j]: TRANS ? in[k0+i][r0+j] (=X[r0+j][k0+i]) : X[r0+i][k0+j]
    tile[row][c4] = v.x; tile[row][c4 + 1] = v.y;
    tile[row][c4 + 2] = v.z; tile[row][c4 + 3] = v.w;
  }
  __syncthreads();
  const int Kc = K >> 5;
#pragma unroll
  for (int half = 0; half < 2; ++half) {
    const int q = half * 256 + t;  // chunk id within tile, 0..511
    const int l = q & 63;
    const int cl = (q >> 6) & 1;
    const int pl = q >> 7;
    const int rl = pl * 16 + (l & 15);
    const int kl = cl * 32 + (l >> 4) * 8;
    u16x8 h8, l8;
#pragma unroll
    for (int j = 0; j < 8; ++j) {
      const float x = TRANS ? tile[kl + j][rl] : tile[rl][kl + j];
      const unsigned short h = f32_to_bf16(x);
      h8[j] = h;
      l8[j] = f32_to_bf16(x - bf16_to_f32(h));
    }
    const size_t o =
        ((size_t)((r0 >> 4) + pl) * Kc + (k0 >> 5) + cl) * 512 + (size_t)l * 8;
    *(u16x8*)&hi[o] = h8;   // consecutive lanes -> contiguous 16B: coalesced
    *(u16x8*)&lo[o] = l8;
  }
}

// ---------- (p0+p1+p2+p3)[2048x2048] -> fragment-order split bf16 ----------
__global__ __launch_bounds__(256) void reduce_pack(
    const float* __restrict__ p0, const float* __restrict__ p1,
    const float* __restrict__ p2, const float* __restrict__ p3,
    unsigned short* __restrict__ hi, unsigned short* __restrict__ lo, int K) {
  __shared__ float tile[64][65];
  const int t = threadIdx.x;
  const int r0 = blockIdx.y * 64;
  const int k0 = blockIdx.x * 64;
  const int lr = t >> 4;
  const int c4 = (t & 15) * 4;
#pragma unroll
  for (int pass = 0; pass < 4; ++pass) {
    const int row = pass * 16 + lr;
    const size_t idx = (size_t)(r0 + row) * K + k0 + c4;
    float4 a = *(const float4*)&p0[idx];
    float4 b = *(const float4*)&p1[idx];
    float4 c = *(const float4*)&p2[idx];
    float4 d = *(const float4*)&p3[idx];
    tile[row][c4]     = (a.x + b.x) + (c.x + d.x);
    tile[row][c4 + 1] = (a.y + b.y) + (c.y + d.y);
    tile[row][c4 + 2] = (a.z + b.z) + (c.z + d.z);
    tile[row][c4 + 3] = (a.w + b.w) + (c.w + d.w);
  }
  __syncthreads();
  const int Kc = K >> 5;
#pragma unroll
  for (int half = 0; half < 2; ++half) {
    const int q = half * 256 + t;
    const int l = q & 63;
    const int cl = (q >> 6) & 1;
    const int pl = q >> 7;
    const int rl = pl * 16 + (l & 15);
    const int kl = cl * 32 + (l >> 4) * 8;
    u16x8 h8, l8;
#pragma unroll
    for (int j = 0; j < 8; ++j) {
      const float x = tile[rl][kl + j];
      const unsigned short h = f32_to_bf16(x);
      h8[j] = h;
      l8[j] = f32_to_bf16(x - bf16_to_f32(h));
    }
    const size_t o =
        ((size_t)((r0 >> 4) + pl) * Kc + (k0 >> 5) + cl) * 512 + (size_t)l * 8;
    *(u16x8*)&hi[o] = h8;
    *(u16x8*)&lo[o] = l8;
  }
}

// ------- LDS-free split-bf16 GEMM over fragment-order operands -------
// C[m][n] = sum_k A[m][k]*B[n][k]. Block 128x128, 2x2 waves, wave 64x64.
// All fragment loads are coalesced 1KB global_load_dwordx4. No LDS/barriers.
template <int KSPLIT, int K>
__global__ __launch_bounds__(256, 2) void gemm_frag(
    const unsigned short* __restrict__ Ahi, const unsigned short* __restrict__ Alo,
    const unsigned short* __restrict__ Bhi, const unsigned short* __restrict__ Blo,
    float* __restrict__ Cf0, float* __restrict__ Cf1,
    float* __restrict__ Cf2, float* __restrict__ Cf3, int M, int N) {
  constexpr int Kc = K >> 5;
  constexpr int iters = Kc / KSPLIT;
  const int t = threadIdx.x;
  const int lane = t & 63;
  const int wave = t >> 6;
  const int wm = wave >> 1, wn = wave & 1;
  const int tileM = blockIdx.y * 128;
  const int tileN = blockIdx.x * 128;
  const int z = (KSPLIT > 1) ? blockIdx.z : 0;
  const int c0 = z * iters;
  float* Cf = Cf0;
  if (KSPLIT > 1) {
    if (z == 1) Cf = Cf1;
    else if (z == 2) Cf = Cf2;
    else if (z == 3) Cf = Cf3;
  }

  unsigned offA[4], offB[4];
#pragma unroll
  for (int i = 0; i < 4; ++i) {
    offA[i] = (unsigned)(((tileM >> 4) + wm * 4 + i) * Kc + c0) * 512 + lane * 8;
    offB[i] = (unsigned)(((tileN >> 4) + wn * 4 + i) * Kc + c0) * 512 + lane * 8;
  }

  f32x4 acc[4][4] = {};

#pragma unroll 2
  for (int it = 0; it < iters; ++it) {
    bf16x8 ah[4], al[4], bh[4], bl[4];
#pragma unroll
    for (int i = 0; i < 4; ++i) {
      ah[i] = *(const bf16x8*)&Ahi[offA[i]];
      al[i] = *(const bf16x8*)&Alo[offA[i]];
      bh[i] = *(const bf16x8*)&Bhi[offB[i]];
      bl[i] = *(const bf16x8*)&Blo[offB[i]];
    }
#pragma unroll
    for (int mi = 0; mi < 4; ++mi)
#pragma unroll
      for (int ni = 0; ni < 4; ++ni) {
        acc[mi][ni] = __builtin_amdgcn_mfma_f32_16x16x32_bf16(ah[mi], bh[ni], acc[mi][ni], 0, 0, 0);
        acc[mi][ni] = __builtin_amdgcn_mfma_f32_16x16x32_bf16(ah[mi], bl[ni], acc[mi][ni], 0, 0, 0);
        acc[mi][ni] = __builtin_amdgcn_mfma_f32_16x16x32_bf16(al[mi], bh[ni], acc[mi][ni], 0, 0, 0);
      }
#pragma unroll
    for (int i = 0; i < 4; ++i) { offA[i] += 512; offB[i] += 512; }
  }

  // epilogue: C/D layout col=lane&15, row=(lane>>4)*4+reg
#pragma unroll
  for (int mi = 0; mi < 4; ++mi)
#pragma unroll
    for (int ni = 0; ni < 4; ++ni)
#pragma unroll
      for (int e = 0; e < 4; ++e) {
        const int row = tileM + wm * 64 + mi * 16 + (lane >> 4) * 4 + e;
        const int col = tileN + wn * 64 + ni * 16 + (lane & 15);
        Cf[(size_t)row * N + col] = acc[mi][ni][e];
      }
}

// -------- fused: out[row] = softmax(out[row] + part[row]) over 4096 cols --------
__global__ __launch_bounds__(256) void reduce_softmax(float* __restrict__ d,
                                                      const float* __restrict__ part,
                                                      int cols) {
  const int row = blockIdx.x;
  float* p = d + (size_t)row * cols;
  const float* q = part + (size_t)row * cols;
  const int t = threadIdx.x;
  const int lane = t & 63;
  const int wave = t >> 6;
  __shared__ float sred[4];

  float4 v[4];
  float m = -3.0e38f;
#pragma unroll
  for (int k = 0; k < 4; ++k) {
    float4 a = *(const float4*)&p[(t + k * 256) * 4];
    float4 b = *(const float4*)&q[(t + k * 256) * 4];
    a.x += b.x; a.y += b.y; a.z += b.z; a.w += b.w;
    v[k] = a;
    m = fmaxf(m, fmaxf(fmaxf(a.x, a.y), fmaxf(a.z, a.w)));
  }
#pragma unroll
  for (int off = 32; off > 0; off >>= 1) m = fmaxf(m, __shfl_xor(m, off, 64));
  if (lane == 0) sred[wave] = m;
  __syncthreads();
  m = fmaxf(fmaxf(sred[0], sred[1]), fmaxf(sred[2], sred[3]));
  __syncthreads();

  float s = 0.f;
#pragma unroll
  for (int k = 0; k < 4; ++k) {
    v[k].x = __expf(v[k].x - m);
    v[k].y = __expf(v[k].y - m);
    v[k].z = __expf(v[k].z - m);
    v[k].w = __expf(v[k].w - m);
    s += (v[k].x + v[k].y) + (v[k].z + v[k].w);
  }
#pragma unroll
  for (int off = 32; off > 0; off >>= 1) s += __shfl_xor(s, off, 64);
  if (lane == 0) sred[wave] = s;
  __syncthreads();
  s = (sred[0] + sred[1]) + (sred[2] + sred[3]);
  const float inv = 1.0f / s;
#pragma unroll
  for (int k = 0; k < 4; ++k) {
    v[k].x *= inv; v[k].y *= inv; v[k].z *= inv; v[k].w *= inv;
    *(float4*)&p[(t + k * 256) * 4] = v[k];
  }
}

extern "C" void kernel_launch(void* const* d_in, const int* in_sizes, int n_in,
                              void* d_out, int out_size, void* d_ws, size_t ws_size,
                              hipStream_t stream) {
  const float* out_state = (const float*)d_in[0];  // [2048, 2048]
  const float* history   = (const float*)d_in[1];  // [4096, 2048]
  const float* W         = (const float*)d_in[2];  // [2048, 2048]
  // d_in[3] = b : softmax-invariant, unused.
  float* out = (float*)d_out;                      // [2048, 4096] fp32

  char* ws = (char*)d_ws;
  const size_t MB = 1ull << 20;
  unsigned short* ohi  = (unsigned short*)(ws + 0 * MB);   // 8 MB  out_state hi (frag order)
  unsigned short* olo  = (unsigned short*)(ws + 8 * MB);   // 8 MB
  unsigned short* wthi = (unsigned short*)(ws + 16 * MB);  // 8 MB  W^T hi (frag order)
  unsigned short* wtlo = (unsigned short*)(ws + 24 * MB);  // 8 MB
  unsigned short* hhi  = (unsigned short*)(ws + 32 * MB);  // 16 MB history hi (frag order)
  unsigned short* hlo  = (unsigned short*)(ws + 48 * MB);  // 16 MB
  float*          pws  = (float*)(ws + 64 * MB);           // 32 MB fp32 partials
  // GEMM1 partials: z0,z1 in pws; z2,z3 in d_out (scratch, 32 MB exact)
  float* g1p0 = pws;
  float* g1p1 = pws + (size_t)STATE_LEN * HIDDEN;
  float* g1p2 = out;
  float* g1p3 = out + (size_t)STATE_LEN * HIDDEN;
  // T (frag order) reuses ws[0:16] (o dead after GEMM1)
  unsigned short* thi = (unsigned short*)(ws + 0 * MB);
  unsigned short* tlo = (unsigned short*)(ws + 8 * MB);

  // 1) pack out_state -> fragment order
  pack_frag<false><<<dim3(HIDDEN / 64, STATE_LEN / 64), 256, 0, stream>>>(
      out_state, HIDDEN, ohi, olo, HIDDEN);
  // 2) pack W^T -> fragment order (operand rows = W cols)
  pack_frag<true><<<dim3(HIDDEN / 64, HIDDEN / 64), 256, 0, stream>>>(
      W, HIDDEN, wthi, wtlo, HIDDEN);
  // 3) pack history -> fragment order
  pack_frag<false><<<dim3(HIDDEN / 64, SEQ_LEN / 64), 256, 0, stream>>>(
      history, HIDDEN, hhi, hlo, HIDDEN);
  // 4) T partials: KSPLIT=4 -> 16x16x4 = 1024 blocks, LDS-free
  gemm_frag<4, HIDDEN>
      <<<dim3(HIDDEN / 128, STATE_LEN / 128, 4), 256, 0, stream>>>(
          ohi, olo, wthi, wtlo, g1p0, g1p1, g1p2, g1p3, STATE_LEN, HIDDEN);
  // 4b) T = sum of 4 partials -> fragment-order split bf16
  reduce_pack<<<dim3(HIDDEN / 64, STATE_LEN / 64), 256, 0, stream>>>(
      g1p0, g1p1, g1p2, g1p3, thi, tlo, HIDDEN);
  // 5) scores partials: KSPLIT=2 -> 32x16x2 = 1024 blocks; z0 -> d_out, z1 -> pws
  gemm_frag<2, HIDDEN>
      <<<dim3(SEQ_LEN / 128, STATE_LEN / 128, 2), 256, 0, stream>>>(
          thi, tlo, hhi, hlo, out, pws, nullptr, nullptr, STATE_LEN, SEQ_LEN);
  // 6) fused partial-add + row softmax
  reduce_softmax<<<STATE_LEN, 256, 0, stream>>>(out, pws, SEQ_LEN);
}

// Round 10
// 273.549 us; speedup vs baseline: 1.8566x; 1.3258x over previous
//
#include <hip/hip_runtime.h>

// out = softmax(out_state @ W @ history^T, axis=-1); bias drops out of softmax.
// STATE_LEN=2048, SEQ_LEN=4096, HIDDEN=2048, fp32 in/out.
// Precision: split-bf16 (hi+lo), 3-term MFMA (hh+hl+lh) -> ~4e-3 absmax.
//
// R10: staged GEMM (R6 structure, best at 41% MfmaUtil) + LDS double-buffer
// with RAW s_barrier and manual s_waitcnt:
//   per iter: issue stage(k+1) -> vmcnt(8) (oldest 8 = tile k's DMAs; vmcnt
//   retires in order) -> s_barrier -> frag reads + 48 MFMAs (tile k+1 DMAs
//   IN FLIGHT the whole time) -> lgkmcnt(0) -> s_barrier (WAR on buffer).
// No __syncthreads in the loop => no vmcnt(0) drain. m139 precedent: this
// barrier pattern is HW-correct. Also: 3 pack kernels fused into 1 (launch
// gaps were ~70us of the 281).

#define STATE_LEN 2048
#define SEQ_LEN   4096
#define HIDDEN    2048

#define BM 128
#define BN 128
#define BK 32

// gfx9 s_waitcnt imm: vmcnt[3:0]=b3:0,[5:4]=b15:14; exp=b6:4; lgkm=b11:8
#define WAIT_VM8   0x0F78  // vmcnt(8),  lgkm=15, exp=7
#define WAIT_VM0   0x0F70  // vmcnt(0),  lgkm=15, exp=7
#define WAIT_LGKM0 0xC07F  // lgkmcnt(0), vmcnt=63, exp=7

typedef __bf16 bf16x8 __attribute__((ext_vector_type(8)));
typedef float f32x4 __attribute__((ext_vector_type(4)));

__device__ __forceinline__ unsigned short f32_to_bf16(float f) {
  unsigned u = __float_as_uint(f);
  u += 0x7FFFu + ((u >> 16) & 1u);   // round-to-nearest-even
  return (unsigned short)(u >> 16);
}
__device__ __forceinline__ float bf16_to_f32(unsigned short h) {
  return __uint_as_float(((unsigned)h) << 16);
}

__device__ __forceinline__ void gld16(const void* g, void* l) {
  __builtin_amdgcn_global_load_lds(
      (const __attribute__((address_space(1))) unsigned int*)g,
      (__attribute__((address_space(3))) unsigned int*)l,
      16, 0, 0);
}

// ---------------- fused pack: splits + W-transpose in ONE kernel ----------------
// jobs by flat blockIdx.x:
//   [0,4096)      : split out_state (4M elems, 1024 elems/block)
//   [4096,12288)  : split history   (8M elems)
//   [12288,13312) : transpose+split W, 64x64 tile per block
__global__ __launch_bounds__(256) void pack_all(
    const float* __restrict__ os, const float* __restrict__ hist,
    const float* __restrict__ W,
    unsigned short* __restrict__ ohi, unsigned short* __restrict__ olo,
    unsigned short* __restrict__ hhi, unsigned short* __restrict__ hlo,
    unsigned short* __restrict__ wthi, unsigned short* __restrict__ wtlo) {
  const int bx = blockIdx.x;
  const int t = threadIdx.x;
  if (bx < 12288) {
    const float* in;
    unsigned short *hi, *lo;
    int i;
    if (bx < 4096) {
      in = os; hi = ohi; lo = olo; i = (bx * 256 + t) * 4;
    } else {
      in = hist; hi = hhi; lo = hlo; i = ((bx - 4096) * 256 + t) * 4;
    }
    float4 v = *(const float4*)&in[i];
    ushort4 h, l;
    h.x = f32_to_bf16(v.x); l.x = f32_to_bf16(v.x - bf16_to_f32(h.x));
    h.y = f32_to_bf16(v.y); l.y = f32_to_bf16(v.y - bf16_to_f32(h.y));
    h.z = f32_to_bf16(v.z); l.z = f32_to_bf16(v.z - bf16_to_f32(h.z));
    h.w = f32_to_bf16(v.w); l.w = f32_to_bf16(v.w - bf16_to_f32(h.w));
    *(ushort4*)&hi[i] = h;
    *(ushort4*)&lo[i] = l;
  } else {
    // transpose 64x64 tile: Wt[k][h] = W[h][k]
    __shared__ float tile[64][65];
    const int bt = bx - 12288;          // 32x32 tiles
    const int h0 = (bt & 31) * 64;      // W row base
    const int k0 = (bt >> 5) * 64;      // W col base
    const int lr = t >> 4;
    const int c4 = (t & 15) * 4;
#pragma unroll
    for (int pass = 0; pass < 4; ++pass) {
      const int row = pass * 16 + lr;
      float4 v = *(const float4*)&W[(size_t)(h0 + row) * HIDDEN + k0 + c4];
      tile[row][c4] = v.x; tile[row][c4 + 1] = v.y;
      tile[row][c4 + 2] = v.z; tile[row][c4 + 3] = v.w;
    }
    __syncthreads();
#pragma unroll
    for (int pass = 0; pass < 4; ++pass) {
      const int kl = pass * 16 + (t >> 4);
      const int hl = (t & 15) * 4;
      ushort4 h4, l4;
#pragma unroll
      for (int j = 0; j < 4; ++j) {
        const float x = tile[hl + j][kl];
        const unsigned short h = f32_to_bf16(x);
        ((unsigned short*)&h4)[j] = h;
        ((unsigned short*)&l4)[j] = f32_to_bf16(x - bf16_to_f32(h));
      }
      const size_t o = (size_t)(k0 + kl) * HIDDEN + h0 + hl;
      *(ushort4*)&wthi[o] = h4;
      *(ushort4*)&wtlo[o] = l4;
    }
  }
}

// ---- p0+p1 -> split bf16 (hi/lo) ----
__global__ __launch_bounds__(256) void reduce_split2(
    const float* __restrict__ p0, const float* __restrict__ p1,
    unsigned short* __restrict__ hi, unsigned short* __restrict__ lo, int n) {
  int i = (blockIdx.x * 256 + threadIdx.x) * 4;
  if (i >= n) return;
  float4 a = *(const float4*)&p0[i];
  float4 b = *(const float4*)&p1[i];
  a.x += b.x; a.y += b.y; a.z += b.z; a.w += b.w;
  ushort4 h, l;
  h.x = f32_to_bf16(a.x); l.x = f32_to_bf16(a.x - bf16_to_f32(h.x));
  h.y = f32_to_bf16(a.y); l.y = f32_to_bf16(a.y - bf16_to_f32(h.y));
  h.z = f32_to_bf16(a.z); l.z = f32_to_bf16(a.z - bf16_to_f32(h.z));
  h.w = f32_to_bf16(a.w); l.w = f32_to_bf16(a.w - bf16_to_f32(h.w));
  *(ushort4*)&hi[i] = h;
  *(ushort4*)&lo[i] = l;
}

// -------- double-buffered split-bf16 GEMM, C[m][n] = sum_k A[m][k]*B[n][k] --------
// A,B row-major K-contig (hi/lo). LDS swizzle: slot (row,c) holds chunk c^((r>>1)&3).
// Double-buffered staging with raw s_barrier + manual vmcnt(8): next tile's DMAs
// stay in flight across the MFMA block. KSPLIT>1: blockIdx.z -> Cf{z} fp32 partial.
template <int KSPLIT>
__global__ __launch_bounds__(256, 2) void gemm_pipe(
    const unsigned short* __restrict__ Ahi, const unsigned short* __restrict__ Alo,
    const unsigned short* __restrict__ Bhi, const unsigned short* __restrict__ Blo,
    float* __restrict__ Cf0, float* __restrict__ Cf1, int M, int N, int K) {
  __shared__ __align__(16) unsigned short sA[2][2][BM * BK];  // [buf][hi/lo]
  __shared__ __align__(16) unsigned short sB[2][2][BN * BK];

  const int t = threadIdx.x;           // 0..255 (4 waves)
  const int tileM = blockIdx.y * BM;
  const int tileN = blockIdx.x * BN;
  const int z = (KSPLIT > 1) ? blockIdx.z : 0;
  const int kBase = z * (K / KSPLIT);
  const int iters = (K / KSPLIT) / BK;
  float* Cf = (KSPLIT > 1 && z == 1) ? Cf1 : Cf0;

  const int rr = t >> 2;               // staging row within a 64-row group
  const int cc = t & 3;                // fixed LDS 16B-slot index

  const int lane = t & 63;
  const int wave = t >> 6;
  const int wm = wave >> 1;            // 2x2 wave grid
  const int wn = wave & 1;
  const int lr = lane & 15;
  const int kqc = lane >> 4;           // fragment k-chunk (16B units)

  f32x4 acc[4][4] = {};

  // stage tile `it` into buffer `buf` (8 gld16 per thread, wave-uniform dest)
  auto stage = [&](int buf, int k0) {
#pragma unroll
    for (int p = 0; p < 2; ++p) {
      const int r = p * 64 + rr;
      const int q = cc ^ ((r >> 1) & 3);  // swizzle via global addr
      const size_t ga = (size_t)(tileM + r) * K + k0 + q * 8;
      const size_t gb = (size_t)(tileN + r) * K + k0 + q * 8;
      const int ls = r * BK + cc * 8;     // == wave_base + lane*16 bytes
      gld16(Ahi + ga, &sA[buf][0][ls]);
      gld16(Alo + ga, &sA[buf][1][ls]);
      gld16(Bhi + gb, &sB[buf][0][ls]);
      gld16(Blo + gb, &sB[buf][1][ls]);
    }
  };

  stage(0, kBase);

  for (int it = 0; it < iters; ++it) {
    const int buf = it & 1;
    if (it + 1 < iters) {
      stage(buf ^ 1, kBase + (it + 1) * BK);
      __builtin_amdgcn_s_waitcnt(WAIT_VM8);  // oldest 8 (= this tile) done
    } else {
      __builtin_amdgcn_s_waitcnt(WAIT_VM0);
    }
    __builtin_amdgcn_s_barrier();            // all waves staged buf

    bf16x8 ah[4], al[4], bh[4], bl[4];
#pragma unroll
    for (int mi = 0; mi < 4; ++mi) {
      const int R = wm * 64 + mi * 16 + lr;
      const int off = R * BK + (kqc ^ ((R >> 1) & 3)) * 8;
      ah[mi] = *(const bf16x8*)&sA[buf][0][off];
      al[mi] = *(const bf16x8*)&sA[buf][1][off];
    }
#pragma unroll
    for (int ni = 0; ni < 4; ++ni) {
      const int R = wn * 64 + ni * 16 + lr;
      const int off = R * BK + (kqc ^ ((R >> 1) & 3)) * 8;
      bh[ni] = *(const bf16x8*)&sB[buf][0][off];
      bl[ni] = *(const bf16x8*)&sB[buf][1][off];
    }
#pragma unroll
    for (int mi = 0; mi < 4; ++mi)
#pragma unroll
      for (int ni = 0; ni < 4; ++ni) {
        acc[mi][ni] = __builtin_amdgcn_mfma_f32_16x16x32_bf16(ah[mi], bh[ni], acc[mi][ni], 0, 0, 0);
        acc[mi][ni] = __builtin_amdgcn_mfma_f32_16x16x32_bf16(ah[mi], bl[ni], acc[mi][ni], 0, 0, 0);
        acc[mi][ni] = __builtin_amdgcn_mfma_f32_16x16x32_bf16(al[mi], bh[ni], acc[mi][ni], 0, 0, 0);
      }

    __builtin_amdgcn_s_waitcnt(WAIT_LGKM0);  // frag reads landed in regs
    __builtin_amdgcn_s_barrier();            // safe to overwrite buf next iter
  }

  // epilogue: C/D layout col=lane&15, row=(lane>>4)*4+reg
#pragma unroll
  for (int mi = 0; mi < 4; ++mi)
#pragma unroll
    for (int ni = 0; ni < 4; ++ni)
#pragma unroll
      for (int e = 0; e < 4; ++e) {
        const int row = tileM + wm * 64 + mi * 16 + (lane >> 4) * 4 + e;
        const int col = tileN + wn * 64 + ni * 16 + lr;
        Cf[(size_t)row * N + col] = acc[mi][ni][e];
      }
}

// ---------------- in-place row softmax over 4096 columns ----------------
__global__ __launch_bounds__(256) void softmax_rows(float* __restrict__ d, int cols) {
  const int row = blockIdx.x;
  float* p = d + (size_t)row * cols;
  const int t = threadIdx.x;
  const int lane = t & 63;
  const int wave = t >> 6;
  __shared__ float sred[4];

  float4 v[4];
  float m = -3.0e38f;
#pragma unroll
  for (int k = 0; k < 4; ++k) {
    v[k] = *(float4*)&p[(t + k * 256) * 4];
    m = fmaxf(m, fmaxf(fmaxf(v[k].x, v[k].y), fmaxf(v[k].z, v[k].w)));
  }
#pragma unroll
  for (int off = 32; off > 0; off >>= 1) m = fmaxf(m, __shfl_xor(m, off, 64));
  if (lane == 0) sred[wave] = m;
  __syncthreads();
  m = fmaxf(fmaxf(sred[0], sred[1]), fmaxf(sred[2], sred[3]));
  __syncthreads();

  float s = 0.f;
#pragma unroll
  for (int k = 0; k < 4; ++k) {
    v[k].x = __expf(v[k].x - m);
    v[k].y = __expf(v[k].y - m);
    v[k].z = __expf(v[k].z - m);
    v[k].w = __expf(v[k].w - m);
    s += (v[k].x + v[k].y) + (v[k].z + v[k].w);
  }
#pragma unroll
  for (int off = 32; off > 0; off >>= 1) s += __shfl_xor(s, off, 64);
  if (lane == 0) sred[wave] = s;
  __syncthreads();
  s = (sred[0] + sred[1]) + (sred[2] + sred[3]);
  const float inv = 1.0f / s;
#pragma unroll
  for (int k = 0; k < 4; ++k) {
    v[k].x *= inv; v[k].y *= inv; v[k].z *= inv; v[k].w *= inv;
    *(float4*)&p[(t + k * 256) * 4] = v[k];
  }
}

extern "C" void kernel_launch(void* const* d_in, const int* in_sizes, int n_in,
                              void* d_out, int out_size, void* d_ws, size_t ws_size,
                              hipStream_t stream) {
  const float* out_state = (const float*)d_in[0];  // [2048, 2048]
  const float* history   = (const float*)d_in[1];  // [4096, 2048]
  const float* W         = (const float*)d_in[2];  // [2048, 2048]
  // d_in[3] = b : softmax-invariant, unused.
  float* out = (float*)d_out;                      // [2048, 4096] fp32

  char* ws = (char*)d_ws;
  const size_t MB = 1ull << 20;
  unsigned short* ohi  = (unsigned short*)(ws + 0 * MB);   // 8 MB
  unsigned short* olo  = (unsigned short*)(ws + 8 * MB);   // 8 MB
  unsigned short* wthi = (unsigned short*)(ws + 16 * MB);  // 8 MB
  unsigned short* wtlo = (unsigned short*)(ws + 24 * MB);  // 8 MB
  unsigned short* hhi  = (unsigned short*)(ws + 32 * MB);  // 16 MB
  unsigned short* hlo  = (unsigned short*)(ws + 48 * MB);  // 16 MB
  float*          pws  = (float*)(ws + 64 * MB);           // 32 MB fp32 partials
  float* g1p0 = pws;
  float* g1p1 = pws + (size_t)STATE_LEN * HIDDEN;
  // T reuses ws[0:16] (out_state split dead after GEMM1)
  unsigned short* thi = (unsigned short*)(ws + 0 * MB);
  unsigned short* tlo = (unsigned short*)(ws + 8 * MB);

  // 1) all packing in one kernel: split os (4096 blocks) + split hist (8192) +
  //    transpose W (1024)
  pack_all<<<13312, 256, 0, stream>>>(out_state, history, W, ohi, olo, hhi, hlo,
                                      wthi, wtlo);
  // 2) T partials: KSPLIT=2 -> 16x16x2 = 512 blocks
  gemm_pipe<2><<<dim3(HIDDEN / BN, STATE_LEN / BM, 2), 256, 0, stream>>>(
      ohi, olo, wthi, wtlo, g1p0, g1p1, STATE_LEN, HIDDEN, HIDDEN);
  // 3) T = p0+p1 -> split bf16
  reduce_split2<<<(STATE_LEN * HIDDEN) / 1024, 256, 0, stream>>>(
      g1p0, g1p1, thi, tlo, STATE_LEN * HIDDEN);
  // 4) scores = T @ history^T -> d_out (KSPLIT=1, 32x16 = 512 blocks)
  gemm_pipe<1><<<dim3(SEQ_LEN / BN, STATE_LEN / BM, 1), 256, 0, stream>>>(
      thi, tlo, hhi, hlo, out, nullptr, STATE_LEN, SEQ_LEN, HIDDEN);
  // 5) row softmax in place
  softmax_rows<<<STATE_LEN, 256, 0, stream>>>(out, SEQ_LEN);
}